// Round 7
// baseline (404.977 us; speedup 1.0000x reference)
//
#include <hip/hip_runtime.h>
#include <stdint.h>

typedef uint16_t u16;
typedef uint32_t u32;
typedef __bf16 bf16_t;
typedef bf16_t bf16x8 __attribute__((ext_vector_type(8)));
typedef float f32x4 __attribute__((ext_vector_type(4)));
typedef u16 u16x4 __attribute__((ext_vector_type(4)));
typedef u16 u16x8 __attribute__((ext_vector_type(8)));

__device__ __forceinline__ float bf2f(u16 v) {
    union { u32 u; float f; } x; x.u = ((u32)v) << 16; return x.f;
}
__device__ __forceinline__ u16 f2bf(float f) {
    union { float f; u32 u; } x; x.f = f;
    u32 r = (x.u + 0x7fffu + ((x.u >> 16) & 1u)) >> 16;
    return (u16)r;
}

// async 16B/lane global->LDS. HW writes lane i at (wave-uniform lds base)+i*16.
__device__ __forceinline__ void gload_lds16(const u16* g, u16* l) {
    __builtin_amdgcn_global_load_lds(
        (const __attribute__((address_space(1))) void*)g,
        (__attribute__((address_space(3))) void*)l,
        16, 0, 0);
}
#define WAIT_ALL() __builtin_amdgcn_s_waitcnt(0)
// wait until <= n vm ops outstanding; exp/lgkm unconstrained (gfx9 encoding)
#define WAITVM(n) __builtin_amdgcn_s_waitcnt(0x0F70 | (n))
// drain LDS ops only; vmcnt unconstrained (vm[3:0]=15, vm[15:14]=3)
#define WAIT_LGKM0() __builtin_amdgcn_s_waitcnt(0xC07F)
#define BARRIER() __builtin_amdgcn_s_barrier()

// ---------------------------------------------------------------------------
// Convert the 4 big fp32 weights -> bf16 in one launch. vec4 units:
// qkvw 786432 | outw 262144 | fc1w 1048576 | fc2w 1048576  (total 3145728)
// ---------------------------------------------------------------------------
__global__ __launch_bounds__(256) void cvt4_kernel(
    const float* __restrict__ s0, const float* __restrict__ s1,
    const float* __restrict__ s2, const float* __restrict__ s3,
    u16* __restrict__ d0, u16* __restrict__ d1,
    u16* __restrict__ d2, u16* __restrict__ d3)
{
    int i = blockIdx.x * 256 + threadIdx.x;
    const float* s; u16* d; int off;
    if (i < 786432)       { s = s0; d = d0; off = i; }
    else if (i < 1048576) { s = s1; d = d1; off = i - 786432; }
    else if (i < 2097152) { s = s2; d = d2; off = i - 1048576; }
    else                  { s = s3; d = d3; off = i - 2097152; }
    f32x4 v = ((const f32x4*)s)[off];
    u16x4 o;
#pragma unroll
    for (int j = 0; j < 4; j++) o[j] = f2bf(v[j]);
    ((u16x4*)d)[off] = o;
}

// ---------------------------------------------------------------------------
// LayerNorm over D=1024, one block (256 thr) per token row. fp32 in, bf16 out.
// ---------------------------------------------------------------------------
__global__ __launch_bounds__(256) void ln_kernel(
    const float* __restrict__ x, const float* __restrict__ g,
    const float* __restrict__ b, u16* __restrict__ out)
{
    const int row = blockIdx.x;
    const int tid = threadIdx.x;
    f32x4 xv = *(const f32x4*)(x + (size_t)row * 1024 + tid * 4);
    float v[4];
    float s = 0.f, s2 = 0.f;
#pragma unroll
    for (int i = 0; i < 4; i++) { v[i] = xv[i]; s += v[i]; s2 += v[i] * v[i]; }
#pragma unroll
    for (int off = 1; off < 64; off <<= 1) {
        s  += __shfl_xor(s, off);
        s2 += __shfl_xor(s2, off);
    }
    __shared__ float ws1[4], ws2[4];
    if ((tid & 63) == 0) { ws1[tid >> 6] = s; ws2[tid >> 6] = s2; }
    __syncthreads();
    s  = ws1[0] + ws1[1] + ws1[2] + ws1[3];
    s2 = ws2[0] + ws2[1] + ws2[2] + ws2[3];
    float mu  = s * (1.0f / 1024.0f);
    float var = s2 * (1.0f / 1024.0f) - mu * mu;
    float rstd = rsqrtf(var + 1e-5f);
    f32x4 gv = *(const f32x4*)(g + tid * 4);
    f32x4 bv = *(const f32x4*)(b + tid * 4);
    u16x4 ov;
#pragma unroll
    for (int i = 0; i < 4; i++)
        ov[i] = f2bf((v[i] - mu) * rstd * gv[i] + bv[i]);
    *(u16x4*)(out + (size_t)row * 1024 + tid * 4) = ov;
}

// ---------------------------------------------------------------------------
// Pipelined GEMM 128x128: C = A @ Bt^T + bias (+gelu) (+fp32 residual).
// Double-buffered LDS; raw s_barrier + partial vmcnt (prefetch stays in
// flight across the compute phase).
// ---------------------------------------------------------------------------
__global__ __launch_bounds__(256, 2) void gemm_bt(
    const u16* __restrict__ A, const u16* __restrict__ Bt,
    const float* __restrict__ bias, const float* res,
    void* C, int N, int K, int lda, int gelu)
{
    __shared__ __align__(16) u16 sA[2][128 * 32];
    __shared__ __align__(16) u16 sB[2][128 * 32];
    const int tid  = threadIdx.x;
    const int wave = tid >> 6, lane = tid & 63;
    const int lm = lane & 15, quad = lane >> 4;
    const int wm = wave >> 1, wn = wave & 1;
    const int row0 = blockIdx.y * 128, col0 = blockIdx.x * 128;
    const int r16 = lane >> 2;
    const int c8  = (lane & 3) * 8;
    const int niter = K >> 5;

    const u16* gsrc;
    size_t gstride;
    int chunk0;
    if (wave < 2) {
        chunk0 = wave * 4;
        gsrc = A + (size_t)(row0 + chunk0 * 16 + r16) * lda + c8;
        gstride = lda;
    } else {
        chunk0 = (wave - 2) * 4;
        gsrc = Bt + (size_t)(col0 + chunk0 * 16 + r16) * K + c8;
        gstride = K;
    }
    u16* lbase0 = (wave < 2) ? &sA[0][chunk0 * 512] : &sB[0][chunk0 * 512];
    u16* lbase1 = (wave < 2) ? &sA[1][chunk0 * 512] : &sB[1][chunk0 * 512];

    f32x4 acc[4][4];
#pragma unroll
    for (int i = 0; i < 4; i++)
#pragma unroll
        for (int j = 0; j < 4; j++) acc[i][j] = f32x4{0.f, 0.f, 0.f, 0.f};

#pragma unroll
    for (int j = 0; j < 4; j++)
        gload_lds16(gsrc + (size_t)(j * 16) * gstride, lbase0 + j * 512);

    for (int k = 0; k < niter; k++) {
        const int cur = k & 1;
        if (k + 1 < niter) {
            const u16* gs = gsrc + (size_t)(k + 1) * 32;
            u16* lb = cur ? lbase0 : lbase1;
#pragma unroll
            for (int j = 0; j < 4; j++)
                gload_lds16(gs + (size_t)(j * 16) * gstride, lb + j * 512);
            WAITVM(4);
        } else {
            WAITVM(0);
        }
        BARRIER();

        bf16x8 af[4], bfr[4];
#pragma unroll
        for (int t = 0; t < 4; t++)
            af[t] = *(const bf16x8*)&sA[cur][(wm * 64 + t * 16 + lm) * 32 + quad * 8];
#pragma unroll
        for (int t = 0; t < 4; t++)
            bfr[t] = *(const bf16x8*)&sB[cur][(wn * 64 + t * 16 + lm) * 32 + quad * 8];
#pragma unroll
        for (int i = 0; i < 4; i++)
#pragma unroll
            for (int j = 0; j < 4; j++)
                acc[i][j] = __builtin_amdgcn_mfma_f32_16x16x32_bf16(af[i], bfr[j], acc[i][j], 0, 0, 0);

        BARRIER();
    }

    float bj[4];
#pragma unroll
    for (int j = 0; j < 4; j++) bj[j] = bias[col0 + wn * 64 + j * 16 + lm];
#pragma unroll
    for (int i = 0; i < 4; i++) {
        int rbase = row0 + wm * 64 + i * 16 + quad * 4;
#pragma unroll
        for (int j = 0; j < 4; j++) {
            int c = col0 + wn * 64 + j * 16 + lm;
#pragma unroll
            for (int r = 0; r < 4; r++) {
                float v = acc[i][j][r] + bj[j];
                if (gelu) v = 0.5f * v * (1.0f + erff(v * 0.70710678118f));
                size_t idx = (size_t)(rbase + r) * N + c;
                if (res) {
                    ((float*)C)[idx] = v + res[idx];
                } else {
                    ((u16*)C)[idx] = f2bf(v);
                }
            }
        }
    }
}

// ---------------------------------------------------------------------------
// Pipelined GEMM 128x64 for N=1024 outputs (proj, FC2): 512 blocks = 2/CU.
// ---------------------------------------------------------------------------
__global__ __launch_bounds__(256, 2) void gemm_bt64(
    const u16* __restrict__ A, const u16* __restrict__ Bt,
    const float* __restrict__ bias, const float* res,
    void* C, int N, int K, int lda, int gelu)
{
    __shared__ __align__(16) u16 sA[2][128 * 32];
    __shared__ __align__(16) u16 sB[2][64 * 32];
    const int tid  = threadIdx.x;
    const int wave = tid >> 6, lane = tid & 63;
    const int lm = lane & 15, quad = lane >> 4;
    const int wm = wave >> 1, wn = wave & 1;
    const int row0 = blockIdx.y * 128, col0 = blockIdx.x * 64;
    const int r16 = lane >> 2;
    const int c8  = (lane & 3) * 8;
    const int niter = K >> 5;

    const u16* gs_[3];
    u16* lb0_[3];
    u16* lb1_[3];
#pragma unroll
    for (int j = 0; j < 3; j++) {
        int cid = wave * 3 + j;
        if (cid < 8) {
            gs_[j] = A + (size_t)(row0 + cid * 16 + r16) * lda + c8;
            lb0_[j] = &sA[0][cid * 512];
            lb1_[j] = &sA[1][cid * 512];
        } else {
            int bc = cid - 8;
            gs_[j] = Bt + (size_t)(col0 + bc * 16 + r16) * K + c8;
            lb0_[j] = &sB[0][bc * 512];
            lb1_[j] = &sB[1][bc * 512];
        }
    }
    const size_t gstride_a = lda, gstride_b = K;
    (void)gstride_a; (void)gstride_b;

    f32x4 acc[4][2];
#pragma unroll
    for (int i = 0; i < 4; i++)
#pragma unroll
        for (int j = 0; j < 2; j++) acc[i][j] = f32x4{0.f, 0.f, 0.f, 0.f};

#pragma unroll
    for (int j = 0; j < 3; j++) gload_lds16(gs_[j], lb0_[j]);

    for (int k = 0; k < niter; k++) {
        const int cur = k & 1;
        if (k + 1 < niter) {
#pragma unroll
            for (int j = 0; j < 3; j++)
                gload_lds16(gs_[j] + (size_t)(k + 1) * 32, cur ? lb0_[j] : lb1_[j]);
            WAITVM(3);
        } else {
            WAITVM(0);
        }
        BARRIER();

        bf16x8 af[4], bfr[2];
#pragma unroll
        for (int t = 0; t < 4; t++)
            af[t] = *(const bf16x8*)&sA[cur][(wm * 64 + t * 16 + lm) * 32 + quad * 8];
#pragma unroll
        for (int t = 0; t < 2; t++)
            bfr[t] = *(const bf16x8*)&sB[cur][(wn * 32 + t * 16 + lm) * 32 + quad * 8];
#pragma unroll
        for (int i = 0; i < 4; i++)
#pragma unroll
            for (int j = 0; j < 2; j++)
                acc[i][j] = __builtin_amdgcn_mfma_f32_16x16x32_bf16(af[i], bfr[j], acc[i][j], 0, 0, 0);

        BARRIER();
    }

    float bj[2];
#pragma unroll
    for (int j = 0; j < 2; j++) bj[j] = bias[col0 + wn * 32 + j * 16 + lm];
#pragma unroll
    for (int i = 0; i < 4; i++) {
        int rbase = row0 + wm * 64 + i * 16 + quad * 4;
#pragma unroll
        for (int j = 0; j < 2; j++) {
            int c = col0 + wn * 32 + j * 16 + lm;
#pragma unroll
            for (int r = 0; r < 4; r++) {
                float v = acc[i][j][r] + bj[j];
                if (gelu) v = 0.5f * v * (1.0f + erff(v * 0.70710678118f));
                size_t idx = (size_t)(rbase + r) * N + c;
                if (res) {
                    ((float*)C)[idx] = v + res[idx];
                } else {
                    ((u16*)C)[idx] = f2bf(v);
                }
            }
        }
    }
}

// ---------------------------------------------------------------------------
// Causal flash attention v3, IN-PLACE on qkv [4096][3072] bf16.
// Block = 4 waves = 64 q rows of one (b,h); double-buffered K (async LDS) and
// V (regs->LDS scatter); raw barriers + partial vmcnt (prefetch in flight
// across compute). Q/K LDS uses chunk-XOR swizzle c' = c ^ (row&7) applied at
// the GLOBAL source address (gload LDS dest is fixed); V^T stored at
// d*64 + ((k>>3 ^ d&7 ^ d>>4)<<3) + (k&7): conflict-free b128 reads, ~2-way
// writes. sP stride 72 (2-way writes = free).
// ---------------------------------------------------------------------------
__global__ __launch_bounds__(256, 3) void attn_kernel(u16* qkv)
{
    __shared__ __align__(16) u16 sQ[64 * 64];
    __shared__ __align__(16) u16 sK[2][64 * 64];
    __shared__ __align__(16) u16 sVT[2][64 * 64];
    __shared__ __align__(16) u16 sP[4 * 16 * 72];

    const int tid  = threadIdx.x;
    const int wave = tid >> 6, lane = tid & 63;
    const int lm = lane & 15, quad = lane >> 4;
    // balance swizzle: pair-fold in x + y-flip
    int xi = blockIdx.x;
    int qz = (xi & 1) ? (31 - (xi >> 1)) : (xi >> 1);
    int qi = ((blockIdx.y >> 3) & 1) ? (31 - qz) : qz;
    const int q0 = qi * 64;
    const int b = blockIdx.y >> 4, h = blockIdx.y & 15;
    const size_t tok0 = (size_t)b * 2048;
    const int qcol = h * 64, kcol = 1024 + h * 64, vcol = 2048 + h * 64;
    const int r8 = lane >> 3;                         // row in 8-row chunk
    const int c8s = (((lane & 7) ^ r8) << 3);         // swizzled source chunk

    // V prefetch constants: thread handles key vkey, dims [vdq, vdq+16)
    const int vkey = tid >> 2;
    const int vq   = tid & 3;
    const int vdq  = vq * 16;
    const u16* vbase = qkv + (tok0 + vkey) * 3072 + vcol + vdq;

    // prologue: stage Q (swizzled), K0, V0-regs; one wait covers Q
#pragma unroll
    for (int j = 0; j < 2; j++) {
        int chunk = wave * 2 + j;
        int r = chunk * 8 + r8;
        gload_lds16(qkv + (tok0 + q0 + r) * 3072 + qcol + c8s, &sQ[chunk * 512]);
    }
#pragma unroll
    for (int j = 0; j < 2; j++) {
        int chunk = wave * 2 + j;
        int r = chunk * 8 + r8;
        gload_lds16(qkv + (tok0 + r) * 3072 + kcol + c8s, &sK[0][chunk * 512]);
    }
    u16x8 va = *(const u16x8*)vbase;
    u16x8 vb = *(const u16x8*)(vbase + 8);
    WAITVM(4);      // Q's 2 gloads done; K0/V0 (4 newest) still in flight
    BARRIER();

    bf16x8 aq[2];
#pragma unroll
    for (int kk = 0; kk < 2; kk++)
        aq[kk] = *(const bf16x8*)
            &sQ[(wave * 16 + lm) * 64 + (((kk * 4 + quad) ^ (lm & 7)) << 3)];

    f32x4 oacc[4];
    float mrun[4], lrun[4];
#pragma unroll
    for (int n = 0; n < 4; n++) oacc[n] = f32x4{0.f, 0.f, 0.f, 0.f};
#pragma unroll
    for (int r = 0; r < 4; r++) { mrun[r] = -1e30f; lrun[r] = 0.f; }

    u16* sPw = &sP[wave * 16 * 72];
    const int ntiles = qi + 1;

    for (int tk = 0; tk < ntiles; tk++) {
        const int cur = tk & 1;
        u16x8 na = va, nb = vb;
        if (tk + 1 < ntiles) {
            const int kb1 = (tk + 1) * 64;
#pragma unroll
            for (int j = 0; j < 2; j++) {
                int chunk = wave * 2 + j;
                int r = chunk * 8 + r8;
                gload_lds16(qkv + (tok0 + kb1 + r) * 3072 + kcol + c8s,
                            &sK[1 - cur][chunk * 512]);
            }
            const u16* vr = vbase + (size_t)kb1 * 3072;
            na = *(const u16x8*)vr;
            nb = *(const u16x8*)(vr + 8);
            WAITVM(4);   // tile-tk K gloads + V regs done; 4 newest in flight
        } else {
            WAITVM(0);
        }
        // scatter V(tk) into sVT[cur]
#pragma unroll
        for (int i = 0; i < 8; i++) {
            int d = vdq + i;
            sVT[cur][d * 64 + ((((vkey >> 3) ^ i ^ vq)) << 3) + (vkey & 7)] = va[i];
        }
#pragma unroll
        for (int i = 0; i < 8; i++) {
            int d = vdq + 8 + i;
            sVT[cur][d * 64 + ((((vkey >> 3) ^ i ^ vq)) << 3) + (vkey & 7)] = vb[i];
        }
        va = na; vb = nb;
        WAIT_LGKM0();    // scatter visible before barrier
        BARRIER();

        const int kb = tk * 64;
        // S = (Q K^T) * scale, causal mask
        float sc[4][4];
#pragma unroll
        for (int n = 0; n < 4; n++) {
            f32x4 s = f32x4{0.f, 0.f, 0.f, 0.f};
#pragma unroll
            for (int kk = 0; kk < 2; kk++) {
                bf16x8 bk = *(const bf16x8*)
                    &sK[cur][(n * 16 + lm) * 64 + (((kk * 4 + quad) ^ (lm & 7)) << 3)];
                s = __builtin_amdgcn_mfma_f32_16x16x32_bf16(aq[kk], bk, s, 0, 0, 0);
            }
            int col  = kb + n * 16 + lm;
            int rowb = q0 + wave * 16 + quad * 4;
#pragma unroll
            for (int r = 0; r < 4; r++)
                sc[n][r] = (col <= rowb + r) ? s[r] * 0.125f : -1e30f;
        }
        // online softmax
#pragma unroll
        for (int r = 0; r < 4; r++) {
            float mx = fmaxf(fmaxf(sc[0][r], sc[1][r]), fmaxf(sc[2][r], sc[3][r]));
#pragma unroll
            for (int off = 1; off < 16; off <<= 1) mx = fmaxf(mx, __shfl_xor(mx, off));
            float mnew  = fmaxf(mrun[r], mx);
            float alpha = __expf(mrun[r] - mnew);
            float sum = 0.f;
#pragma unroll
            for (int n = 0; n < 4; n++) {
                float p = __expf(sc[n][r] - mnew);
                sc[n][r] = p;
                sum += p;
            }
#pragma unroll
            for (int off = 1; off < 16; off <<= 1) sum += __shfl_xor(sum, off);
            lrun[r] = lrun[r] * alpha + sum;
            mrun[r] = mnew;
#pragma unroll
            for (int n = 0; n < 4; n++) oacc[n][r] *= alpha;
        }
        // P: C-layout regs -> per-wave LDS (stride 72) -> A-layout frags
#pragma unroll
        for (int n = 0; n < 4; n++)
#pragma unroll
            for (int r = 0; r < 4; r++)
                sPw[(quad * 4 + r) * 72 + n * 16 + lm] = f2bf(sc[n][r]);
        bf16x8 ap[2];
#pragma unroll
        for (int kk = 0; kk < 2; kk++)
            ap[kk] = *(const bf16x8*)&sPw[lm * 72 + kk * 32 + quad * 8];
        // O += P V
#pragma unroll
        for (int n = 0; n < 4; n++)
#pragma unroll
            for (int kk = 0; kk < 2; kk++) {
                bf16x8 bv = *(const bf16x8*)
                    &sVT[cur][(n * 16 + lm) * 64 +
                              ((((kk * 4 + quad) ^ (lm & 7) ^ n)) << 3)];
                oacc[n] = __builtin_amdgcn_mfma_f32_16x16x32_bf16(ap[kk], bv, oacc[n], 0, 0, 0);
            }

        BARRIER();   // all reads of buf[cur] done before tk+1 overwrites it
    }

    // write O into the Q columns of qkv (in-place)
    {
        int rowb = q0 + wave * 16 + quad * 4;
#pragma unroll
        for (int r = 0; r < 4; r++) {
            float inv = 1.0f / lrun[r];
#pragma unroll
            for (int n = 0; n < 4; n++) {
                int d = n * 16 + lm;
                qkv[(tok0 + rowb + r) * 3072 + qcol + d] = f2bf(oacc[n][r] * inv);
            }
        }
    }
}

// ---------------------------------------------------------------------------
extern "C" void kernel_launch(void* const* d_in, const int* in_sizes, int n_in,
                              void* d_out, int out_size, void* d_ws, size_t ws_size,
                              hipStream_t stream)
{
    (void)in_sizes; (void)n_in; (void)out_size; (void)ws_size;
    const float* x    = (const float*)d_in[0];
    const float* ln1g = (const float*)d_in[1];
    const float* ln1b = (const float*)d_in[2];
    const float* qkvwF= (const float*)d_in[3];
    const float* qkvb = (const float*)d_in[4];
    const float* outwF= (const float*)d_in[5];
    const float* outb = (const float*)d_in[6];
    const float* ln2g = (const float*)d_in[7];
    const float* ln2b = (const float*)d_in[8];
    const float* fc1wF= (const float*)d_in[9];
    const float* fc1b = (const float*)d_in[10];
    const float* fc2wF= (const float*)d_in[11];
    const float* fc2b = (const float*)d_in[12];
    float* out = (float*)d_out;
    u16*   ws  = (u16*)d_ws;
    const int M1 = 1 << 20;

    u16* qkvw = ws;
    u16* outw = ws + 3 * M1;
    u16* qkvB = ws + 4 * M1;
    u16* ff1  = ws;
    u16* fc1w = ws + 16 * M1;
    u16* fc2w = ws + 20 * M1;
    u16* h    = ws + 24 * M1;

    // 0. all four weight conversions in one launch
    cvt4_kernel<<<12288, 256, 0, stream>>>(qkvwF, outwF, fc1wF, fc2wF,
                                           qkvw, outw, fc1w, fc2w);

    // 1. h = LN1(x)
    ln_kernel<<<4096, 256, 0, stream>>>(x, ln1g, ln1b, h);
    // 2. qkvB = h @ qkv_w^T + qkv_b
    gemm_bt<<<dim3(24, 32), 256, 0, stream>>>(h, qkvw, qkvb, nullptr, qkvB,
                                              3072, 1024, 1024, 0);
    // 3. causal flash attention (pipelined), O -> Q cols of qkvB
    attn_kernel<<<dim3(32, 32), 256, 0, stream>>>(qkvB);
    // 4. x1(=d_out, fp32) = x + O @ out_w^T + out_b
    gemm_bt64<<<dim3(16, 32), 256, 0, stream>>>(qkvB, outw, outb, x, out,
                                                1024, 1024, 3072, 0);
    // 5. h = LN2(x1)
    ln_kernel<<<4096, 256, 0, stream>>>(out, ln2g, ln2b, h);
    // 6. ff1 = gelu(h @ fc1_w^T + fc1_b)
    gemm_bt<<<dim3(32, 32), 256, 0, stream>>>(h, fc1w, fc1b, nullptr, ff1,
                                              4096, 1024, 1024, 1);
    // 7. out = x1 + ff1 @ fc2_w^T + fc2_b   (fp32, in-place residual)
    gemm_bt64<<<dim3(16, 32), 256, 0, stream>>>(ff1, fc2w, fc2b, out, out,
                                                1024, 4096, 4096, 0);
}

// Round 8
// 368.007 us; speedup vs baseline: 1.1005x; 1.1005x over previous
//
#include <hip/hip_runtime.h>
#include <stdint.h>

typedef uint16_t u16;
typedef uint32_t u32;
typedef __bf16 bf16_t;
typedef bf16_t bf16x8 __attribute__((ext_vector_type(8)));
typedef float f32x4 __attribute__((ext_vector_type(4)));
typedef u16 u16x4 __attribute__((ext_vector_type(4)));
typedef u16 u16x8 __attribute__((ext_vector_type(8)));

__device__ __forceinline__ float bf2f(u16 v) {
    union { u32 u; float f; } x; x.u = ((u32)v) << 16; return x.f;
}
__device__ __forceinline__ u16 f2bf(float f) {
    union { float f; u32 u; } x; x.f = f;
    u32 r = (x.u + 0x7fffu + ((x.u >> 16) & 1u)) >> 16;
    return (u16)r;
}

// async 16B/lane global->LDS. HW writes lane i at (wave-uniform lds base)+i*16.
__device__ __forceinline__ void gload_lds16(const u16* g, u16* l) {
    __builtin_amdgcn_global_load_lds(
        (const __attribute__((address_space(1))) void*)g,
        (__attribute__((address_space(3))) void*)l,
        16, 0, 0);
}
// wait until <= n vm ops outstanding; exp/lgkm unconstrained (gfx9 encoding)
#define WAITVM(n) __builtin_amdgcn_s_waitcnt(0x0F70 | (n))
// drain LDS ops only; vmcnt unconstrained
#define WAIT_LGKM0() __builtin_amdgcn_s_waitcnt(0xC07F)
#define BARRIER() __builtin_amdgcn_s_barrier()

// ---------------------------------------------------------------------------
// Convert the 4 big fp32 weights -> bf16 in one launch.
// ---------------------------------------------------------------------------
__global__ __launch_bounds__(256) void cvt4_kernel(
    const float* __restrict__ s0, const float* __restrict__ s1,
    const float* __restrict__ s2, const float* __restrict__ s3,
    u16* __restrict__ d0, u16* __restrict__ d1,
    u16* __restrict__ d2, u16* __restrict__ d3)
{
    int i = blockIdx.x * 256 + threadIdx.x;
    const float* s; u16* d; int off;
    if (i < 786432)       { s = s0; d = d0; off = i; }
    else if (i < 1048576) { s = s1; d = d1; off = i - 786432; }
    else if (i < 2097152) { s = s2; d = d2; off = i - 1048576; }
    else                  { s = s3; d = d3; off = i - 2097152; }
    f32x4 v = ((const f32x4*)s)[off];
    u16x4 o;
#pragma unroll
    for (int j = 0; j < 4; j++) o[j] = f2bf(v[j]);
    ((u16x4*)d)[off] = o;
}

// ---------------------------------------------------------------------------
// LayerNorm over D=1024, one block (256 thr) per token row. fp32 in, bf16 out.
// ---------------------------------------------------------------------------
__global__ __launch_bounds__(256) void ln_kernel(
    const float* __restrict__ x, const float* __restrict__ g,
    const float* __restrict__ b, u16* __restrict__ out)
{
    const int row = blockIdx.x;
    const int tid = threadIdx.x;
    f32x4 xv = *(const f32x4*)(x + (size_t)row * 1024 + tid * 4);
    float v[4];
    float s = 0.f, s2 = 0.f;
#pragma unroll
    for (int i = 0; i < 4; i++) { v[i] = xv[i]; s += v[i]; s2 += v[i] * v[i]; }
#pragma unroll
    for (int off = 1; off < 64; off <<= 1) {
        s  += __shfl_xor(s, off);
        s2 += __shfl_xor(s2, off);
    }
    __shared__ float ws1[4], ws2[4];
    if ((tid & 63) == 0) { ws1[tid >> 6] = s; ws2[tid >> 6] = s2; }
    __syncthreads();
    s  = ws1[0] + ws1[1] + ws1[2] + ws1[3];
    s2 = ws2[0] + ws2[1] + ws2[2] + ws2[3];
    float mu  = s * (1.0f / 1024.0f);
    float var = s2 * (1.0f / 1024.0f) - mu * mu;
    float rstd = rsqrtf(var + 1e-5f);
    f32x4 gv = *(const f32x4*)(g + tid * 4);
    f32x4 bv = *(const f32x4*)(b + tid * 4);
    u16x4 ov;
#pragma unroll
    for (int i = 0; i < 4; i++)
        ov[i] = f2bf((v[i] - mu) * rstd * gv[i] + bv[i]);
    *(u16x4*)(out + (size_t)row * 1024 + tid * 4) = ov;
}

// ---------------------------------------------------------------------------
// Pipelined GEMM 128x128: C = A @ Bt^T + bias (+gelu) (+fp32 residual).
// Double-buffered LDS; raw s_barrier + partial vmcnt.
// ---------------------------------------------------------------------------
__global__ __launch_bounds__(256, 2) void gemm_bt(
    const u16* __restrict__ A, const u16* __restrict__ Bt,
    const float* __restrict__ bias, const float* res,
    void* C, int N, int K, int lda, int gelu)
{
    __shared__ __align__(16) u16 sA[2][128 * 32];
    __shared__ __align__(16) u16 sB[2][128 * 32];
    const int tid  = threadIdx.x;
    const int wave = tid >> 6, lane = tid & 63;
    const int lm = lane & 15, quad = lane >> 4;
    const int wm = wave >> 1, wn = wave & 1;
    const int row0 = blockIdx.y * 128, col0 = blockIdx.x * 128;
    const int r16 = lane >> 2;
    const int c8  = (lane & 3) * 8;
    const int niter = K >> 5;

    const u16* gsrc;
    size_t gstride;
    int chunk0;
    if (wave < 2) {
        chunk0 = wave * 4;
        gsrc = A + (size_t)(row0 + chunk0 * 16 + r16) * lda + c8;
        gstride = lda;
    } else {
        chunk0 = (wave - 2) * 4;
        gsrc = Bt + (size_t)(col0 + chunk0 * 16 + r16) * K + c8;
        gstride = K;
    }
    u16* lbase0 = (wave < 2) ? &sA[0][chunk0 * 512] : &sB[0][chunk0 * 512];
    u16* lbase1 = (wave < 2) ? &sA[1][chunk0 * 512] : &sB[1][chunk0 * 512];

    f32x4 acc[4][4];
#pragma unroll
    for (int i = 0; i < 4; i++)
#pragma unroll
        for (int j = 0; j < 4; j++) acc[i][j] = f32x4{0.f, 0.f, 0.f, 0.f};

#pragma unroll
    for (int j = 0; j < 4; j++)
        gload_lds16(gsrc + (size_t)(j * 16) * gstride, lbase0 + j * 512);

    for (int k = 0; k < niter; k++) {
        const int cur = k & 1;
        if (k + 1 < niter) {
            const u16* gs = gsrc + (size_t)(k + 1) * 32;
            u16* lb = cur ? lbase0 : lbase1;
#pragma unroll
            for (int j = 0; j < 4; j++)
                gload_lds16(gs + (size_t)(j * 16) * gstride, lb + j * 512);
            WAITVM(4);
        } else {
            WAITVM(0);
        }
        BARRIER();

        bf16x8 af[4], bfr[4];
#pragma unroll
        for (int t = 0; t < 4; t++)
            af[t] = *(const bf16x8*)&sA[cur][(wm * 64 + t * 16 + lm) * 32 + quad * 8];
#pragma unroll
        for (int t = 0; t < 4; t++)
            bfr[t] = *(const bf16x8*)&sB[cur][(wn * 64 + t * 16 + lm) * 32 + quad * 8];
#pragma unroll
        for (int i = 0; i < 4; i++)
#pragma unroll
            for (int j = 0; j < 4; j++)
                acc[i][j] = __builtin_amdgcn_mfma_f32_16x16x32_bf16(af[i], bfr[j], acc[i][j], 0, 0, 0);

        BARRIER();
    }

    float bj[4];
#pragma unroll
    for (int j = 0; j < 4; j++) bj[j] = bias[col0 + wn * 64 + j * 16 + lm];
#pragma unroll
    for (int i = 0; i < 4; i++) {
        int rbase = row0 + wm * 64 + i * 16 + quad * 4;
#pragma unroll
        for (int j = 0; j < 4; j++) {
            int c = col0 + wn * 64 + j * 16 + lm;
#pragma unroll
            for (int r = 0; r < 4; r++) {
                float v = acc[i][j][r] + bj[j];
                if (gelu) v = 0.5f * v * (1.0f + erff(v * 0.70710678118f));
                size_t idx = (size_t)(rbase + r) * N + c;
                if (res) {
                    ((float*)C)[idx] = v + res[idx];
                } else {
                    ((u16*)C)[idx] = f2bf(v);
                }
            }
        }
    }
}

// ---------------------------------------------------------------------------
// Pipelined GEMM 128x64 for N=1024 outputs (proj, FC2): 512 blocks = 2/CU.
// ---------------------------------------------------------------------------
__global__ __launch_bounds__(256, 2) void gemm_bt64(
    const u16* __restrict__ A, const u16* __restrict__ Bt,
    const float* __restrict__ bias, const float* res,
    void* C, int N, int K, int lda, int gelu)
{
    __shared__ __align__(16) u16 sA[2][128 * 32];
    __shared__ __align__(16) u16 sB[2][64 * 32];
    const int tid  = threadIdx.x;
    const int wave = tid >> 6, lane = tid & 63;
    const int lm = lane & 15, quad = lane >> 4;
    const int wm = wave >> 1, wn = wave & 1;
    const int row0 = blockIdx.y * 128, col0 = blockIdx.x * 64;
    const int r16 = lane >> 2;
    const int c8  = (lane & 3) * 8;
    const int niter = K >> 5;

    const u16* gs_[3];
    u16* lb0_[3];
    u16* lb1_[3];
#pragma unroll
    for (int j = 0; j < 3; j++) {
        int cid = wave * 3 + j;
        if (cid < 8) {
            gs_[j] = A + (size_t)(row0 + cid * 16 + r16) * lda + c8;
            lb0_[j] = &sA[0][cid * 512];
            lb1_[j] = &sA[1][cid * 512];
        } else {
            int bc = cid - 8;
            gs_[j] = Bt + (size_t)(col0 + bc * 16 + r16) * K + c8;
            lb0_[j] = &sB[0][bc * 512];
            lb1_[j] = &sB[1][bc * 512];
        }
    }

    f32x4 acc[4][2];
#pragma unroll
    for (int i = 0; i < 4; i++)
#pragma unroll
        for (int j = 0; j < 2; j++) acc[i][j] = f32x4{0.f, 0.f, 0.f, 0.f};

#pragma unroll
    for (int j = 0; j < 3; j++) gload_lds16(gs_[j], lb0_[j]);

    for (int k = 0; k < niter; k++) {
        const int cur = k & 1;
        if (k + 1 < niter) {
#pragma unroll
            for (int j = 0; j < 3; j++)
                gload_lds16(gs_[j] + (size_t)(k + 1) * 32, cur ? lb0_[j] : lb1_[j]);
            WAITVM(3);
        } else {
            WAITVM(0);
        }
        BARRIER();

        bf16x8 af[4], bfr[2];
#pragma unroll
        for (int t = 0; t < 4; t++)
            af[t] = *(const bf16x8*)&sA[cur][(wm * 64 + t * 16 + lm) * 32 + quad * 8];
#pragma unroll
        for (int t = 0; t < 2; t++)
            bfr[t] = *(const bf16x8*)&sB[cur][(wn * 32 + t * 16 + lm) * 32 + quad * 8];
#pragma unroll
        for (int i = 0; i < 4; i++)
#pragma unroll
            for (int j = 0; j < 2; j++)
                acc[i][j] = __builtin_amdgcn_mfma_f32_16x16x32_bf16(af[i], bfr[j], acc[i][j], 0, 0, 0);

        BARRIER();
    }

    float bj[2];
#pragma unroll
    for (int j = 0; j < 2; j++) bj[j] = bias[col0 + wn * 32 + j * 16 + lm];
#pragma unroll
    for (int i = 0; i < 4; i++) {
        int rbase = row0 + wm * 64 + i * 16 + quad * 4;
#pragma unroll
        for (int j = 0; j < 2; j++) {
            int c = col0 + wn * 32 + j * 16 + lm;
#pragma unroll
            for (int r = 0; r < 4; r++) {
                float v = acc[i][j][r] + bj[j];
                if (gelu) v = 0.5f * v * (1.0f + erff(v * 0.70710678118f));
                size_t idx = (size_t)(rbase + r) * N + c;
                if (res) {
                    ((float*)C)[idx] = v + res[idx];
                } else {
                    ((u16*)C)[idx] = f2bf(v);
                }
            }
        }
    }
}

// ---------------------------------------------------------------------------
// Causal flash attention v4, IN-PLACE on qkv [4096][3072] bf16.
// Block = 4 waves = 64 q rows of one (b,h); K/V double-buffered (async LDS /
// regs->scatter), raw barriers + partial vmcnt. S computed TRANSPOSED
// (S^T = K·Q^T) so each q-row's scores live in one lane: softmax row
// reduction = in-lane ops + 2 shuffles (vs 32 shuffles for S layout).
// sP overlays sQ (Q is in regs after prologue; per-wave lgkm drain before the
// in-loop barrier orders sQ reads vs sP writes). LDS 40 KB -> 4 blocks/CU.
// All tiles chunk-XOR swizzled: G[row][c] at LDS[row][c ^ (row&7)] (chunks of
// 8 u16); V^T chunk c' = c ^ (d&7) ^ (d>>4).
// ---------------------------------------------------------------------------
__global__ __launch_bounds__(256, 4) void attn_kernel(u16* qkv)
{
    __shared__ __align__(16) u16 sQP[64 * 64];     // Q tile, then P scratch
    __shared__ __align__(16) u16 sK[2][64 * 64];
    __shared__ __align__(16) u16 sVT[2][64 * 64];

    const int tid  = threadIdx.x;
    const int wave = tid >> 6, lane = tid & 63;
    const int lm = lane & 15, quad = lane >> 4;
    // balance swizzle: pair-fold in x + y-flip
    int xi = blockIdx.x;
    int qz = (xi & 1) ? (31 - (xi >> 1)) : (xi >> 1);
    int qi = ((blockIdx.y >> 3) & 1) ? (31 - qz) : qz;
    const int q0 = qi * 64;
    const int b = blockIdx.y >> 4, h = blockIdx.y & 15;
    const size_t tok0 = (size_t)b * 2048;
    const int qcol = h * 64, kcol = 1024 + h * 64, vcol = 2048 + h * 64;
    const int r8 = lane >> 3;                  // row in 8-row staging chunk
    const int c8s = (((lane & 7) ^ r8) << 3);  // swizzled source chunk

    // V prefetch: thread handles key vkey, dims [vq*16, vq*16+16)
    const int vkey = tid >> 2;
    const int vq   = tid & 3;
    const int vdq  = vq * 16;
    const u16* vbase = qkv + (tok0 + vkey) * 3072 + vcol + vdq;

    // prologue: stage Q (swizzled), K0, V0-regs
#pragma unroll
    for (int j = 0; j < 2; j++) {
        int chunk = wave * 2 + j;
        int r = chunk * 8 + r8;
        gload_lds16(qkv + (tok0 + q0 + r) * 3072 + qcol + c8s, &sQP[chunk * 512]);
    }
#pragma unroll
    for (int j = 0; j < 2; j++) {
        int chunk = wave * 2 + j;
        int r = chunk * 8 + r8;
        gload_lds16(qkv + (tok0 + r) * 3072 + kcol + c8s, &sK[0][chunk * 512]);
    }
    u16x8 va = *(const u16x8*)vbase;
    u16x8 vb = *(const u16x8*)(vbase + 8);
    WAITVM(4);      // Q's 2 gloads done; K0/V0 (4 newest) still in flight
    BARRIER();

    // Q fragments: row = wave*16+lm (row&7 = lm&7)
    bf16x8 aq[2];
#pragma unroll
    for (int kk = 0; kk < 2; kk++)
        aq[kk] = *(const bf16x8*)
            &sQP[(wave * 16 + lm) * 64 + (((kk * 4 + quad) ^ (lm & 7)) << 3)];

    f32x4 oacc[4];                 // O C-layout: row=quad*4+r, col=n*16+lm
    float mrun = -1e30f, lrun = 0.f;   // per-lane stats for qrow = lm
#pragma unroll
    for (int n = 0; n < 4; n++) oacc[n] = f32x4{0.f, 0.f, 0.f, 0.f};

    u16* sPw = &sQP[wave * 16 * 64];   // per-wave P region (overlays sQ)
    const int ntiles = qi + 1;
    const int qrow_lane = q0 + wave * 16 + lm;   // this lane's softmax row

    for (int tk = 0; tk < ntiles; tk++) {
        const int cur = tk & 1;
        u16x8 na = va, nb = vb;
        if (tk + 1 < ntiles) {
            const int kb1 = (tk + 1) * 64;
#pragma unroll
            for (int j = 0; j < 2; j++) {
                int chunk = wave * 2 + j;
                int r = chunk * 8 + r8;
                gload_lds16(qkv + (tok0 + kb1 + r) * 3072 + kcol + c8s,
                            &sK[1 - cur][chunk * 512]);
            }
            const u16* vr = vbase + (size_t)kb1 * 3072;
            na = *(const u16x8*)vr;
            nb = *(const u16x8*)(vr + 8);
            WAITVM(4);
        } else {
            WAITVM(0);
        }
        // scatter V(tk) into sVT[cur]
#pragma unroll
        for (int i = 0; i < 8; i++) {
            int d = vdq + i;
            sVT[cur][d * 64 + ((((vkey >> 3) ^ i ^ vq)) << 3) + (vkey & 7)] = va[i];
        }
#pragma unroll
        for (int i = 0; i < 8; i++) {
            int d = vdq + 8 + i;
            sVT[cur][d * 64 + ((((vkey >> 3) ^ i ^ vq)) << 3) + (vkey & 7)] = vb[i];
        }
        va = na; vb = nb;
        WAIT_LGKM0();    // own scatter + own sQ/sP LDS ops drained
        BARRIER();

        const int kb = tk * 64;
        // S^T = (K Q^T) * scale: a-frag = K rows (keys), b-frag = Q rows.
        // C-layout: col = lm = qrow_local, row = quad*4+r = key_local.
        float sc[4][4];
#pragma unroll
        for (int n = 0; n < 4; n++) {            // key block n*16
            f32x4 s = f32x4{0.f, 0.f, 0.f, 0.f};
#pragma unroll
            for (int kk = 0; kk < 2; kk++) {
                bf16x8 ak = *(const bf16x8*)
                    &sK[cur][(n * 16 + lm) * 64 + (((kk * 4 + quad) ^ (lm & 7)) << 3)];
                s = __builtin_amdgcn_mfma_f32_16x16x32_bf16(ak, aq[kk], s, 0, 0, 0);
            }
#pragma unroll
            for (int r = 0; r < 4; r++) {
                int key = kb + n * 16 + quad * 4 + r;
                sc[n][r] = (key <= qrow_lane) ? s[r] * 0.125f : -1e30f;
            }
        }
        // softmax for qrow=lm: in-lane reduce + 2 cross-quad shuffles
        float mx = sc[0][0];
#pragma unroll
        for (int n = 0; n < 4; n++)
#pragma unroll
            for (int r = 0; r < 4; r++) mx = fmaxf(mx, sc[n][r]);
        mx = fmaxf(mx, __shfl_xor(mx, 16));
        mx = fmaxf(mx, __shfl_xor(mx, 32));
        float mnew  = fmaxf(mrun, mx);
        float alpha = __expf(mrun - mnew);
        float sum = 0.f;
#pragma unroll
        for (int n = 0; n < 4; n++)
#pragma unroll
            for (int r = 0; r < 4; r++) {
                float p = __expf(sc[n][r] - mnew);
                sc[n][r] = p;
                sum += p;
            }
        sum += __shfl_xor(sum, 16);
        sum += __shfl_xor(sum, 32);
        lrun = lrun * alpha + sum;
        mrun = mnew;
        // transpose alpha to O's C-layout rows (quad*4+r), rescale O
        float aT[4];
#pragma unroll
        for (int r = 0; r < 4; r++) aT[r] = __shfl(alpha, quad * 4 + r);
#pragma unroll
        for (int n = 0; n < 4; n++)
#pragma unroll
            for (int r = 0; r < 4; r++) oacc[n][r] *= aT[r];
        // P^T (C-layout) -> sPw[qrow=lm][key] with chunk-XOR swizzle
#pragma unroll
        for (int n = 0; n < 4; n++)
#pragma unroll
            for (int r = 0; r < 4; r++) {
                int key = n * 16 + quad * 4 + r;
                int addr = lm * 64 + (((key >> 3) ^ (lm & 7)) << 3) + (key & 7);
                sPw[addr] = f2bf(sc[n][r]);
            }
        // P A-layout frags: row = lm, key chunk (kk*4+quad)^(lm&7)
        bf16x8 ap[2];
#pragma unroll
        for (int kk = 0; kk < 2; kk++)
            ap[kk] = *(const bf16x8*)
                &sPw[lm * 64 + (((kk * 4 + quad) ^ (lm & 7)) << 3)];
        // O += P V
#pragma unroll
        for (int n = 0; n < 4; n++)
#pragma unroll
            for (int kk = 0; kk < 2; kk++) {
                bf16x8 bv = *(const bf16x8*)
                    &sVT[cur][(n * 16 + lm) * 64 +
                              ((((kk * 4 + quad) ^ (lm & 7) ^ n)) << 3)];
                oacc[n] = __builtin_amdgcn_mfma_f32_16x16x32_bf16(ap[kk], bv, oacc[n], 0, 0, 0);
            }

        BARRIER();   // all reads of buf[cur] done before tk+1 overwrites
    }

    // write O (C-layout rows quad*4+r); 1/l transposed like alpha
    {
        float lT[4];
#pragma unroll
        for (int r = 0; r < 4; r++) lT[r] = __shfl(lrun, quad * 4 + r);
        int rowb = q0 + wave * 16 + quad * 4;
#pragma unroll
        for (int r = 0; r < 4; r++) {
            float inv = 1.0f / lT[r];
#pragma unroll
            for (int n = 0; n < 4; n++) {
                int d = n * 16 + lm;
                qkv[(tok0 + rowb + r) * 3072 + qcol + d] = f2bf(oacc[n][r] * inv);
            }
        }
    }
}

// ---------------------------------------------------------------------------
extern "C" void kernel_launch(void* const* d_in, const int* in_sizes, int n_in,
                              void* d_out, int out_size, void* d_ws, size_t ws_size,
                              hipStream_t stream)
{
    (void)in_sizes; (void)n_in; (void)out_size; (void)ws_size;
    const float* x    = (const float*)d_in[0];
    const float* ln1g = (const float*)d_in[1];
    const float* ln1b = (const float*)d_in[2];
    const float* qkvwF= (const float*)d_in[3];
    const float* qkvb = (const float*)d_in[4];
    const float* outwF= (const float*)d_in[5];
    const float* outb = (const float*)d_in[6];
    const float* ln2g = (const float*)d_in[7];
    const float* ln2b = (const float*)d_in[8];
    const float* fc1wF= (const float*)d_in[9];
    const float* fc1b = (const float*)d_in[10];
    const float* fc2wF= (const float*)d_in[11];
    const float* fc2b = (const float*)d_in[12];
    float* out = (float*)d_out;
    u16*   ws  = (u16*)d_ws;
    const int M1 = 1 << 20;

    u16* qkvw = ws;
    u16* outw = ws + 3 * M1;
    u16* qkvB = ws + 4 * M1;
    u16* ff1  = ws;
    u16* fc1w = ws + 16 * M1;
    u16* fc2w = ws + 20 * M1;
    u16* h    = ws + 24 * M1;

    cvt4_kernel<<<12288, 256, 0, stream>>>(qkvwF, outwF, fc1wF, fc2wF,
                                           qkvw, outw, fc1w, fc2w);

    ln_kernel<<<4096, 256, 0, stream>>>(x, ln1g, ln1b, h);
    gemm_bt<<<dim3(24, 32), 256, 0, stream>>>(h, qkvw, qkvb, nullptr, qkvB,
                                              3072, 1024, 1024, 0);
    attn_kernel<<<dim3(32, 32), 256, 0, stream>>>(qkvB);
    gemm_bt64<<<dim3(16, 32), 256, 0, stream>>>(qkvB, outw, outb, x, out,
                                                1024, 1024, 3072, 0);
    ln_kernel<<<4096, 256, 0, stream>>>(out, ln2g, ln2b, h);
    gemm_bt<<<dim3(32, 32), 256, 0, stream>>>(h, fc1w, fc1b, nullptr, ff1,
                                              4096, 1024, 1024, 1);
    gemm_bt64<<<dim3(16, 32), 256, 0, stream>>>(ff1, fc2w, fc2b, out, out,
                                                1024, 4096, 4096, 0);
}